// Round 1
// 1321.238 us; speedup vs baseline: 1.1474x; 1.1474x over previous
//
#include <hip/hip_runtime.h>
#include <hip/hip_bf16.h>

#define B_SZ      512
#define INPUT_DIM 1536
#define MAMBA_DIM 1024
#define OUT_DIM   1024
#define D_STATE   128
#define HEADDIM   64
#define D_INNER   2048
#define NHEADS    32
#define CONV_DIM  2304
#define D_IN_PROJ 4384   // 2*2048 + 2*128 + 32

__device__ __forceinline__ float silu_precise(float x) {
    return x / (1.0f + expf(-x));
}

// ---------------------------------------------------------------------------
// SGEMM: C[M,N] = A[M,K] @ W[K,N] (+ bias[N] if bias != nullptr)
// Tile 64x64, BK=32, 256 threads, 4x4 microtile. M % 64 == 0, K % 32 == 0,
// N % 4 == 0 (bounds-checked on N).
// ---------------------------------------------------------------------------
__global__ __launch_bounds__(256) void sgemm_kernel(
    const float* __restrict__ A, const float* __restrict__ W,
    const float* __restrict__ bias, float* __restrict__ C,
    int M, int N, int K)
{
    __shared__ float As[32][64];      // [k][m]
    __shared__ float Bs[32][64];      // [k][n]

    const int t   = threadIdx.x;
    const int bn0 = blockIdx.x * 64;
    const int bm0 = blockIdx.y * 64;
    const int tr  = t >> 4;           // 0..15
    const int tc  = t & 15;           // 0..15

    float acc[4][4] = {};

    for (int k0 = 0; k0 < K; k0 += 32) {
        // A tile: 64 rows x 32 k = 512 float4 loads (2 per thread)
        #pragma unroll
        for (int i = 0; i < 2; ++i) {
            int idx = t + i * 256;
            int row = idx >> 3;
            int c4  = (idx & 7) * 4;
            float4 v = *(const float4*)(A + (size_t)(bm0 + row) * K + k0 + c4);
            As[c4 + 0][row] = v.x;
            As[c4 + 1][row] = v.y;
            As[c4 + 2][row] = v.z;
            As[c4 + 3][row] = v.w;
        }
        // B tile: 32 k x 64 n = 512 float4 loads (2 per thread)
        #pragma unroll
        for (int i = 0; i < 2; ++i) {
            int idx = t + i * 256;
            int kr  = idx >> 4;
            int c4  = (idx & 15) * 4;
            int n   = bn0 + c4;
            float4 v = make_float4(0.f, 0.f, 0.f, 0.f);
            if (n < N) v = *(const float4*)(W + (size_t)(k0 + kr) * N + n);
            *(float4*)&Bs[kr][c4] = v;
        }
        __syncthreads();

        #pragma unroll
        for (int k = 0; k < 32; ++k) {
            float4 a = *(const float4*)&As[k][tr * 4];
            float4 b = *(const float4*)&Bs[k][tc * 4];
            float av[4] = {a.x, a.y, a.z, a.w};
            float bv[4] = {b.x, b.y, b.z, b.w};
            #pragma unroll
            for (int i = 0; i < 4; ++i)
                #pragma unroll
                for (int j = 0; j < 4; ++j)
                    acc[i][j] += av[i] * bv[j];
        }
        __syncthreads();
    }

    #pragma unroll
    for (int i = 0; i < 4; ++i) {
        int m = bm0 + tr * 4 + i;
        #pragma unroll
        for (int j = 0; j < 4; ++j) {
            int n = bn0 + tc * 4 + j;
            if (n < N) {
                float v = acc[i][j];
                if (bias) v += bias[n];
                C[(size_t)m * N + n] = v;
            }
        }
    }
}

// ---------------------------------------------------------------------------
// RMSNorm over 1024 cols (+ optional SiLU). One block (256 thr) per row.
// ---------------------------------------------------------------------------
template <bool SILU>
__global__ __launch_bounds__(256) void rmsnorm_kernel(
    const float* __restrict__ X, const float* __restrict__ g,
    float* __restrict__ Y)
{
    const int row = blockIdx.x;
    const float* x = X + (size_t)row * 1024;
    float4 v = *(const float4*)(x + threadIdx.x * 4);
    float ss = v.x * v.x + v.y * v.y + v.z * v.z + v.w * v.w;
    #pragma unroll
    for (int off = 32; off > 0; off >>= 1) ss += __shfl_down(ss, off);

    __shared__ float wsum[4];
    const int wid = threadIdx.x >> 6;
    if ((threadIdx.x & 63) == 0) wsum[wid] = ss;
    __syncthreads();
    const float tot = wsum[0] + wsum[1] + wsum[2] + wsum[3];
    const float rs = 1.0f / sqrtf(tot * (1.0f / 1024.0f) + 1e-5f);

    float4 gv = *(const float4*)(g + threadIdx.x * 4);
    float4 o;
    o.x = v.x * rs * gv.x;
    o.y = v.y * rs * gv.y;
    o.z = v.z * rs * gv.z;
    o.w = v.w * rs * gv.w;
    if (SILU) {
        o.x = silu_precise(o.x);
        o.y = silu_precise(o.y);
        o.z = silu_precise(o.z);
        o.w = silu_precise(o.w);
    }
    *(float4*)(Y + (size_t)row * 1024 + threadIdx.x * 4) = o;
}

// ---------------------------------------------------------------------------
// Conv state shift + depthwise conv + SiLU. One thread per (b, c).
// Writes conv_state_new (output 1) and xbc_conv (ws).
// ---------------------------------------------------------------------------
__global__ __launch_bounds__(256) void conv_kernel(
    const float* __restrict__ conv_state, const float* __restrict__ zx,
    const float* __restrict__ conv_w, const float* __restrict__ conv_b,
    float* __restrict__ conv_state_out, float* __restrict__ xbc_out)
{
    const int gid = blockIdx.x * 256 + threadIdx.x;  // b*CONV_DIM + c
    const int b = gid / CONV_DIM;
    const int c = gid - b * CONV_DIM;

    float4 cs = *(const float4*)(conv_state + (size_t)gid * 4);
    float xn = zx[(size_t)b * D_IN_PROJ + D_INNER + c];
    float4 w = *(const float4*)(conv_w + c * 4);

    float s = cs.y * w.x + cs.z * w.y + cs.w * w.z + xn * w.w + conv_b[c];
    float r = silu_precise(s);

    float4 o = make_float4(cs.y, cs.z, cs.w, xn);
    *(float4*)(conv_state_out + (size_t)gid * 4) = o;
    xbc_out[gid] = r;
}

// ---------------------------------------------------------------------------
// SSM state update + y.  Block = (head h, batch b), 256 threads.
//
// COALESCED mapping: element index e = t*4 + i*1024 within the 64x128 slab.
//   n0 = (t & 31) * 4   (each thread owns ONE 4-wide n-chunk, loads b/c once)
//   p  = (t >> 5) + 8*i
// Per VMEM instruction a wave touches a CONTIGUOUS 1024-B segment (load and
// store), vs the previous layout's 64 distinct 128-B lines per instruction
// (which showed up as 1.22x write amplification + 29% HBM in rocprof).
// y-reduction: 32-lane shfl_xor tree over the n-owning lanes.
// ---------------------------------------------------------------------------
__global__ __launch_bounds__(256) void ssm_kernel(
    const float* __restrict__ ssm_state, const float* __restrict__ xbc,
    const float* __restrict__ zx, const float* __restrict__ A_log,
    const float* __restrict__ dt_bias, const float* __restrict__ Dp,
    float* __restrict__ ssm_out, float* __restrict__ yz)
{
    const int h = blockIdx.x;   // 0..31
    const int b = blockIdx.y;   // 0..511
    const int t = threadIdx.x;  // 0..255
    const int lane_n = t & 31;       // n-group lane within 32-lane cluster
    const int n0 = lane_n * 4;       // n base (0..124)
    const int pg = t >> 5;           // 0..7

    float dtv = zx[(size_t)b * D_IN_PROJ + (D_INNER + CONV_DIM) + h] + dt_bias[h];
    dtv = (dtv > 20.f) ? dtv : log1pf(expf(dtv));
    const float a  = -expf(A_log[h]);
    const float da = expf(dtv * a);
    const float dcoef = Dp[h];

    const float* xrow = xbc + (size_t)b * CONV_DIM;

    // each thread loads its b/c chunk ONCE
    const float4 bb = *(const float4*)(xrow + D_INNER + n0);
    const float4 cc = *(const float4*)(xrow + D_INNER + D_STATE + n0);

    const size_t slab = ((size_t)b * NHEADS + h) * (HEADDIM * D_STATE);
    const float* sp = ssm_state + slab;
    float*       so = ssm_out   + slab;

    #pragma unroll
    for (int i = 0; i < 8; ++i) {
        const int p = pg + i * 8;
        const float xh = xrow[h * HEADDIM + p];
        const float coef = dtv * xh;

        const size_t off = (size_t)p * D_STATE + n0;
        float4 s = *(const float4*)(sp + off);
        float4 ns;
        ns.x = s.x * da + coef * bb.x;
        ns.y = s.y * da + coef * bb.y;
        ns.z = s.z * da + coef * bb.z;
        ns.w = s.w * da + coef * bb.w;
        *(float4*)(so + off) = ns;

        float y = ns.x * cc.x + ns.y * cc.y + ns.z * cc.z + ns.w * cc.w;
        // reduce over the 32 lanes that share p (masks <32 stay within the
        // 32-lane halves of the wave64, which is exactly our group)
        y += __shfl_xor(y, 16);
        y += __shfl_xor(y, 8);
        y += __shfl_xor(y, 4);
        y += __shfl_xor(y, 2);
        y += __shfl_xor(y, 1);

        if (lane_n == 0) {
            float z = zx[(size_t)b * D_IN_PROJ + h * HEADDIM + p];
            float yv = y + dcoef * xh;
            yz[(size_t)b * D_INNER + h * HEADDIM + p] = yv * silu_precise(z);
        }
    }
}

// ---------------------------------------------------------------------------

extern "C" void kernel_launch(void* const* d_in, const int* in_sizes, int n_in,
                              void* d_out, int out_size, void* d_ws, size_t ws_size,
                              hipStream_t stream)
{
    const float* x          = (const float*)d_in[0];   // 512 x 1536
    const float* conv_state = (const float*)d_in[1];   // 512 x 2304 x 4
    const float* ssm_state  = (const float*)d_in[2];   // 512 x 32 x 64 x 128
    const float* w_in       = (const float*)d_in[3];   // 1536 x 1024
    const float* b_in       = (const float*)d_in[4];   // 1024
    const float* g_in       = (const float*)d_in[5];   // 1024
    const float* W_inproj   = (const float*)d_in[6];   // 1024 x 4384
    const float* conv_w     = (const float*)d_in[7];   // 2304 x 4
    const float* conv_b     = (const float*)d_in[8];   // 2304
    const float* A_log      = (const float*)d_in[9];   // 32
    const float* dt_bias    = (const float*)d_in[10];  // 32
    const float* Dp         = (const float*)d_in[11];  // 32
    const float* W_mamba_out= (const float*)d_in[12];  // 2048 x 1024
    const float* w_out      = (const float*)d_in[13];  // 1024 x 1024
    const float* b_out      = (const float*)d_in[14];  // 1024
    const float* g_outnorm  = (const float*)d_in[15];  // 1024

    float* out_y    = (float*)d_out;                                   // 512*1024
    float* out_conv = out_y + (size_t)B_SZ * OUT_DIM;                  // 512*2304*4
    float* out_ssm  = out_conv + (size_t)B_SZ * CONV_DIM * 4;          // 512*32*64*128

    float* ws  = (float*)d_ws;
    float* t1  = ws;                                  // 512*1024 (gemm1 out)
    float* h   = t1  + (size_t)B_SZ * MAMBA_DIM;      // 512*1024
    float* zx  = h   + (size_t)B_SZ * MAMBA_DIM;      // 512*4384
    float* xbc = zx  + (size_t)B_SZ * D_IN_PROJ;      // 512*2304
    float* yzb = xbc + (size_t)B_SZ * CONV_DIM;       // 512*2048
    float* u   = yzb + (size_t)B_SZ * D_INNER;        // 512*1024
    float* t2  = u   + (size_t)B_SZ * MAMBA_DIM;      // 512*1024

    // 1) t1 = x @ w_in + b_in
    sgemm_kernel<<<dim3(MAMBA_DIM / 64, B_SZ / 64), 256, 0, stream>>>(
        x, w_in, b_in, t1, B_SZ, MAMBA_DIM, INPUT_DIM);
    // 2) h = silu(rmsnorm(t1, g_in))
    rmsnorm_kernel<true><<<B_SZ, 256, 0, stream>>>(t1, g_in, h);
    // 3) zx = h @ W_inproj
    sgemm_kernel<<<dim3((D_IN_PROJ + 63) / 64, B_SZ / 64), 256, 0, stream>>>(
        h, W_inproj, nullptr, zx, B_SZ, D_IN_PROJ, MAMBA_DIM);
    // 4) conv state shift + conv + silu
    conv_kernel<<<(B_SZ * CONV_DIM) / 256, 256, 0, stream>>>(
        conv_state, zx, conv_w, conv_b, out_conv, xbc);
    // 5) ssm update + gated y
    ssm_kernel<<<dim3(NHEADS, B_SZ), 256, 0, stream>>>(
        ssm_state, xbc, zx, A_log, dt_bias, Dp, out_ssm, yzb);
    // 6) u = yz @ W_mamba_out
    sgemm_kernel<<<dim3(MAMBA_DIM / 64, B_SZ / 64), 256, 0, stream>>>(
        yzb, W_mamba_out, nullptr, u, B_SZ, MAMBA_DIM, D_INNER);
    // 7) t2 = u @ w_out + b_out
    sgemm_kernel<<<dim3(OUT_DIM / 64, B_SZ / 64), 256, 0, stream>>>(
        u, w_out, b_out, t2, B_SZ, OUT_DIM, MAMBA_DIM);
    // 8) out_y = rmsnorm(t2, g_outnorm)
    rmsnorm_kernel<false><<<B_SZ, 256, 0, stream>>>(t2, g_outnorm, out_y);
}

// Round 2
// 1273.010 us; speedup vs baseline: 1.1909x; 1.0379x over previous
//
#include <hip/hip_runtime.h>
#include <hip/hip_bf16.h>

#define B_SZ      512
#define INPUT_DIM 1536
#define MAMBA_DIM 1024
#define OUT_DIM   1024
#define D_STATE   128
#define HEADDIM   64
#define D_INNER   2048
#define NHEADS    32
#define CONV_DIM  2304
#define D_IN_PROJ 4384   // 2*2048 + 2*128 + 32

__device__ __forceinline__ float silu_precise(float x) {
    return x / (1.0f + expf(-x));
}

// ---------------------------------------------------------------------------
// Zero-fill (float4 grid-stride). Clears the split-K accumulation buffers.
// ---------------------------------------------------------------------------
__global__ __launch_bounds__(256) void zero_kernel(float4* __restrict__ p, int n4)
{
    int i = blockIdx.x * 256 + threadIdx.x;
    const int stride = gridDim.x * 256;
    const float4 z = make_float4(0.f, 0.f, 0.f, 0.f);
    for (; i < n4; i += stride) p[i] = z;
}

// ---------------------------------------------------------------------------
// Split-K SGEMM: C[M,N] += A[M,K] @ W[K,N] (+ bias[N] on split 0).
// Tile 64x64, BK=32, 256 threads, 4x4 microtile. blockIdx.z = K-split.
// C must be pre-zeroed. Kper % 32 == 0, M % 64 == 0, N % 4 == 0.
// As padded to stride 68 floats (272 B, float4-aligned): staging-write bank
// conflict drops from 8-way (stride 64 ≡ 0 mod 32 banks) to 4-way.
// ---------------------------------------------------------------------------
__global__ __launch_bounds__(256) void sgemm_splitk_kernel(
    const float* __restrict__ A, const float* __restrict__ W,
    const float* __restrict__ bias, float* __restrict__ C,
    int M, int N, int K, int Kper)
{
    __shared__ float As[32][68];      // [k][m], padded
    __shared__ float Bs[32][64];      // [k][n]

    const int t   = threadIdx.x;
    const int bn0 = blockIdx.x * 64;
    const int bm0 = blockIdx.y * 64;
    const int kz0 = blockIdx.z * Kper;
    const int tr  = t >> 4;           // 0..15
    const int tc  = t & 15;           // 0..15

    float acc[4][4] = {};

    for (int kk = 0; kk < Kper; kk += 32) {
        const int k0 = kz0 + kk;
        // A tile: 64 rows x 32 k (transpose into [k][m])
        #pragma unroll
        for (int i = 0; i < 2; ++i) {
            int idx = t + i * 256;
            int row = idx >> 3;
            int c4  = (idx & 7) * 4;
            float4 v = *(const float4*)(A + (size_t)(bm0 + row) * K + k0 + c4);
            As[c4 + 0][row] = v.x;
            As[c4 + 1][row] = v.y;
            As[c4 + 2][row] = v.z;
            As[c4 + 3][row] = v.w;
        }
        // B tile: 32 k x 64 n
        #pragma unroll
        for (int i = 0; i < 2; ++i) {
            int idx = t + i * 256;
            int kr  = idx >> 4;
            int c4  = (idx & 15) * 4;
            int n   = bn0 + c4;
            float4 v = make_float4(0.f, 0.f, 0.f, 0.f);
            if (n < N) v = *(const float4*)(W + (size_t)(k0 + kr) * N + n);
            *(float4*)&Bs[kr][c4] = v;
        }
        __syncthreads();

        #pragma unroll
        for (int k = 0; k < 32; ++k) {
            float4 a = *(const float4*)&As[k][tr * 4];
            float4 b = *(const float4*)&Bs[k][tc * 4];
            float av[4] = {a.x, a.y, a.z, a.w};
            float bv[4] = {b.x, b.y, b.z, b.w};
            #pragma unroll
            for (int i = 0; i < 4; ++i)
                #pragma unroll
                for (int j = 0; j < 4; ++j)
                    acc[i][j] += av[i] * bv[j];
        }
        __syncthreads();
    }

    const bool addb = (bias != nullptr) && (blockIdx.z == 0);
    #pragma unroll
    for (int i = 0; i < 4; ++i) {
        int m = bm0 + tr * 4 + i;
        #pragma unroll
        for (int j = 0; j < 4; ++j) {
            int n = bn0 + tc * 4 + j;
            if (n < N) {
                float v = acc[i][j];
                if (addb) v += bias[n];
                atomicAdd(&C[(size_t)m * N + n], v);
            }
        }
    }
}

// ---------------------------------------------------------------------------
// RMSNorm over 1024 cols (+ optional SiLU). One block (256 thr) per row.
// ---------------------------------------------------------------------------
template <bool SILU>
__global__ __launch_bounds__(256) void rmsnorm_kernel(
    const float* __restrict__ X, const float* __restrict__ g,
    float* __restrict__ Y)
{
    const int row = blockIdx.x;
    const float* x = X + (size_t)row * 1024;
    float4 v = *(const float4*)(x + threadIdx.x * 4);
    float ss = v.x * v.x + v.y * v.y + v.z * v.z + v.w * v.w;
    #pragma unroll
    for (int off = 32; off > 0; off >>= 1) ss += __shfl_down(ss, off);

    __shared__ float wsum[4];
    const int wid = threadIdx.x >> 6;
    if ((threadIdx.x & 63) == 0) wsum[wid] = ss;
    __syncthreads();
    const float tot = wsum[0] + wsum[1] + wsum[2] + wsum[3];
    const float rs = 1.0f / sqrtf(tot * (1.0f / 1024.0f) + 1e-5f);

    float4 gv = *(const float4*)(g + threadIdx.x * 4);
    float4 o;
    o.x = v.x * rs * gv.x;
    o.y = v.y * rs * gv.y;
    o.z = v.z * rs * gv.z;
    o.w = v.w * rs * gv.w;
    if (SILU) {
        o.x = silu_precise(o.x);
        o.y = silu_precise(o.y);
        o.z = silu_precise(o.z);
        o.w = silu_precise(o.w);
    }
    *(float4*)(Y + (size_t)row * 1024 + threadIdx.x * 4) = o;
}

// ---------------------------------------------------------------------------
// Conv state shift + depthwise conv + SiLU. One thread per (b, c).
// ---------------------------------------------------------------------------
__global__ __launch_bounds__(256) void conv_kernel(
    const float* __restrict__ conv_state, const float* __restrict__ zx,
    const float* __restrict__ conv_w, const float* __restrict__ conv_b,
    float* __restrict__ conv_state_out, float* __restrict__ xbc_out)
{
    const int gid = blockIdx.x * 256 + threadIdx.x;  // b*CONV_DIM + c
    const int b = gid / CONV_DIM;
    const int c = gid - b * CONV_DIM;

    float4 cs = *(const float4*)(conv_state + (size_t)gid * 4);
    float xn = zx[(size_t)b * D_IN_PROJ + D_INNER + c];
    float4 w = *(const float4*)(conv_w + c * 4);

    float s = cs.y * w.x + cs.z * w.y + cs.w * w.z + xn * w.w + conv_b[c];
    float r = silu_precise(s);

    float4 o = make_float4(cs.y, cs.z, cs.w, xn);
    *(float4*)(conv_state_out + (size_t)gid * 4) = o;
    xbc_out[gid] = r;
}

// ---------------------------------------------------------------------------
// SSM state update + y.  Block = (head h, batch b), 256 threads.
// Coalesced mapping: n0 = (t&31)*4 (thread owns one 4-wide n-chunk),
// p = (t>>5) + 8*i. Wave touches contiguous 1024-B segments per VMEM op.
// ---------------------------------------------------------------------------
__global__ __launch_bounds__(256) void ssm_kernel(
    const float* __restrict__ ssm_state, const float* __restrict__ xbc,
    const float* __restrict__ zx, const float* __restrict__ A_log,
    const float* __restrict__ dt_bias, const float* __restrict__ Dp,
    float* __restrict__ ssm_out, float* __restrict__ yz)
{
    const int h = blockIdx.x;   // 0..31
    const int b = blockIdx.y;   // 0..511
    const int t = threadIdx.x;  // 0..255
    const int lane_n = t & 31;
    const int n0 = lane_n * 4;
    const int pg = t >> 5;

    float dtv = zx[(size_t)b * D_IN_PROJ + (D_INNER + CONV_DIM) + h] + dt_bias[h];
    dtv = (dtv > 20.f) ? dtv : log1pf(expf(dtv));
    const float a  = -expf(A_log[h]);
    const float da = expf(dtv * a);
    const float dcoef = Dp[h];

    const float* xrow = xbc + (size_t)b * CONV_DIM;

    const float4 bb = *(const float4*)(xrow + D_INNER + n0);
    const float4 cc = *(const float4*)(xrow + D_INNER + D_STATE + n0);

    const size_t slab = ((size_t)b * NHEADS + h) * (HEADDIM * D_STATE);
    const float* sp = ssm_state + slab;
    float*       so = ssm_out   + slab;

    #pragma unroll
    for (int i = 0; i < 8; ++i) {
        const int p = pg + i * 8;
        const float xh = xrow[h * HEADDIM + p];
        const float coef = dtv * xh;

        const size_t off = (size_t)p * D_STATE + n0;
        float4 s = *(const float4*)(sp + off);
        float4 ns;
        ns.x = s.x * da + coef * bb.x;
        ns.y = s.y * da + coef * bb.y;
        ns.z = s.z * da + coef * bb.z;
        ns.w = s.w * da + coef * bb.w;
        *(float4*)(so + off) = ns;

        float y = ns.x * cc.x + ns.y * cc.y + ns.z * cc.z + ns.w * cc.w;
        y += __shfl_xor(y, 16);
        y += __shfl_xor(y, 8);
        y += __shfl_xor(y, 4);
        y += __shfl_xor(y, 2);
        y += __shfl_xor(y, 1);

        if (lane_n == 0) {
            float z = zx[(size_t)b * D_IN_PROJ + h * HEADDIM + p];
            float yv = y + dcoef * xh;
            yz[(size_t)b * D_INNER + h * HEADDIM + p] = yv * silu_precise(z);
        }
    }
}

// ---------------------------------------------------------------------------

extern "C" void kernel_launch(void* const* d_in, const int* in_sizes, int n_in,
                              void* d_out, int out_size, void* d_ws, size_t ws_size,
                              hipStream_t stream)
{
    const float* x          = (const float*)d_in[0];   // 512 x 1536
    const float* conv_state = (const float*)d_in[1];   // 512 x 2304 x 4
    const float* ssm_state  = (const float*)d_in[2];   // 512 x 32 x 64 x 128
    const float* w_in       = (const float*)d_in[3];   // 1536 x 1024
    const float* b_in       = (const float*)d_in[4];   // 1024
    const float* g_in       = (const float*)d_in[5];   // 1024
    const float* W_inproj   = (const float*)d_in[6];   // 1024 x 4384
    const float* conv_w     = (const float*)d_in[7];   // 2304 x 4
    const float* conv_b     = (const float*)d_in[8];   // 2304
    const float* A_log      = (const float*)d_in[9];   // 32
    const float* dt_bias    = (const float*)d_in[10];  // 32
    const float* Dp         = (const float*)d_in[11];  // 32
    const float* W_mamba_out= (const float*)d_in[12];  // 2048 x 1024
    const float* w_out      = (const float*)d_in[13];  // 1024 x 1024
    const float* b_out      = (const float*)d_in[14];  // 1024
    const float* g_outnorm  = (const float*)d_in[15];  // 1024

    float* out_y    = (float*)d_out;                                   // 512*1024
    float* out_conv = out_y + (size_t)B_SZ * OUT_DIM;                  // 512*2304*4
    float* out_ssm  = out_conv + (size_t)B_SZ * CONV_DIM * 4;          // 512*32*64*128

    // GEMM outputs FIRST and contiguous, so one zero-fill covers all four.
    float* ws  = (float*)d_ws;
    float* t1  = ws;                                  // 512*1024 (gemm1 out)
    float* zx  = t1  + (size_t)B_SZ * MAMBA_DIM;      // 512*4384 (gemm2 out)
    float* u   = zx  + (size_t)B_SZ * D_IN_PROJ;      // 512*1024 (gemm3 out)
    float* t2  = u   + (size_t)B_SZ * MAMBA_DIM;      // 512*1024 (gemm4 out)
    float* h   = t2  + (size_t)B_SZ * MAMBA_DIM;      // 512*1024
    float* xbc = h   + (size_t)B_SZ * MAMBA_DIM;      // 512*2304
    float* yzb = xbc + (size_t)B_SZ * CONV_DIM;       // 512*2048

    const int gemm_out_floats = B_SZ * (MAMBA_DIM + D_IN_PROJ + MAMBA_DIM + MAMBA_DIM);

    // 0) zero the split-K accumulation buffers (t1, zx, u, t2 contiguous)
    zero_kernel<<<2048, 256, 0, stream>>>((float4*)ws, gemm_out_floats / 4);

    // 1) t1 += x @ w_in + b_in          (splits=8, Kper=192, 1024 blocks)
    sgemm_splitk_kernel<<<dim3(MAMBA_DIM / 64, B_SZ / 64, 8), 256, 0, stream>>>(
        x, w_in, b_in, t1, B_SZ, MAMBA_DIM, INPUT_DIM, INPUT_DIM / 8);
    // 2) h = silu(rmsnorm(t1, g_in))
    rmsnorm_kernel<true><<<B_SZ, 256, 0, stream>>>(t1, g_in, h);
    // 3) zx += h @ W_inproj             (splits=4, Kper=256, 2208 blocks)
    sgemm_splitk_kernel<<<dim3((D_IN_PROJ + 63) / 64, B_SZ / 64, 4), 256, 0, stream>>>(
        h, W_inproj, nullptr, zx, B_SZ, D_IN_PROJ, MAMBA_DIM, MAMBA_DIM / 4);
    // 4) conv state shift + conv + silu
    conv_kernel<<<(B_SZ * CONV_DIM) / 256, 256, 0, stream>>>(
        conv_state, zx, conv_w, conv_b, out_conv, xbc);
    // 5) ssm update + gated y
    ssm_kernel<<<dim3(NHEADS, B_SZ), 256, 0, stream>>>(
        ssm_state, xbc, zx, A_log, dt_bias, Dp, out_ssm, yzb);
    // 6) u += yz @ W_mamba_out          (splits=8, Kper=256, 1024 blocks)
    sgemm_splitk_kernel<<<dim3(MAMBA_DIM / 64, B_SZ / 64, 8), 256, 0, stream>>>(
        yzb, W_mamba_out, nullptr, u, B_SZ, MAMBA_DIM, D_INNER, D_INNER / 8);
    // 7) t2 += u @ w_out + b_out        (splits=8, Kper=128, 1024 blocks)
    sgemm_splitk_kernel<<<dim3(OUT_DIM / 64, B_SZ / 64, 8), 256, 0, stream>>>(
        u, w_out, b_out, t2, B_SZ, OUT_DIM, MAMBA_DIM, MAMBA_DIM / 8);
    // 8) out_y = rmsnorm(t2, g_outnorm)
    rmsnorm_kernel<false><<<B_SZ, 256, 0, stream>>>(t2, g_outnorm, out_y);
}

// Round 3
// 1101.914 us; speedup vs baseline: 1.3758x; 1.1553x over previous
//
#include <hip/hip_runtime.h>

#define B_SZ      512
#define INPUT_DIM 1536
#define MAMBA_DIM 1024
#define OUT_DIM   1024
#define D_STATE   128
#define HEADDIM   64
#define D_INNER   2048
#define NHEADS    32
#define CONV_DIM  2304
#define D_IN_PROJ 4384   // 2*2048 + 2*128 + 32

typedef short  short8 __attribute__((ext_vector_type(8)));
typedef float  f32x4  __attribute__((ext_vector_type(4)));

__device__ __forceinline__ float silu_precise(float x) {
    return x / (1.0f + expf(-x));
}

// fp32 -> bf16 round-to-nearest-even (bit trick, no header deps)
__device__ __forceinline__ ushort f2bf(float f) {
    uint32_t u = __float_as_uint(f);
    u += 0x7FFFu + ((u >> 16) & 1u);
    return (ushort)(u >> 16);
}
__device__ __forceinline__ float bf2f(ushort h) {
    return __uint_as_float(((uint32_t)h) << 16);
}
// split x into hi (bf16 RN) + lo (bf16 of residual); hi+lo ~= x to 2^-16 rel.
__device__ __forceinline__ void split_bf(float x, ushort& hi, ushort& lo) {
    hi = f2bf(x);
    lo = f2bf(x - bf2f(hi));
}

// ---------------------------------------------------------------------------
// Zero-fill (float4 grid-stride). Clears the split-K accumulation buffers.
// ---------------------------------------------------------------------------
__global__ __launch_bounds__(256) void zero_kernel(float4* __restrict__ p, int n4)
{
    int i = blockIdx.x * 256 + threadIdx.x;
    const int stride = gridDim.x * 256;
    const float4 z = make_float4(0.f, 0.f, 0.f, 0.f);
    for (; i < n4; i += stride) p[i] = z;
}

// ---------------------------------------------------------------------------
// Split-bf16 3-pass MFMA GEMM:  C[M,N] += A[M,K] @ W[K,N]  (+bias on split 0)
//
// fp32 operands are split ON THE FLY during LDS staging into bf16 (hi, lo)
// planes; each k-tile does 3 MFMA passes (hi*hi + hi*lo + lo*hi) with fp32
// accumulation -> ~2^-16 relative error (fp32-like), at matrix-core rate.
//
// Tile 128x128, BK=32, 256 threads = 4 waves; each wave owns a 64x64
// quadrant = 4x4 fragments of v_mfma_f32_16x16x32_bf16.
// LDS planes padded to 40 bf16 (80 B) per row to spread banks.
// Fragment layout (m89-verified C/D; standard A/B):
//   A[m][k]: m = lane&15, k = (lane>>4)*8 + j  (8 contiguous bf16)
//   B[k][n]: n = lane&15, k = (lane>>4)*8 + j  -> LDS B stored [n][k]
//   D[m][n]: n = lane&15, m = (lane>>4)*4 + reg
// Epilogue: atomicAdd into pre-zeroed C (split-K). Kper%32==0, M%128==0,
// N bounds-checked (N%4==0 required).
// ---------------------------------------------------------------------------
__global__ __launch_bounds__(256) void gemm_bf16x3_splitk(
    const float* __restrict__ A, const float* __restrict__ W,
    const float* __restrict__ bias, float* __restrict__ C,
    int M, int N, int K, int Kper)
{
    __shared__ ushort As_hi[128][40];
    __shared__ ushort As_lo[128][40];
    __shared__ ushort Bs_hi[128][40];   // [n][k]
    __shared__ ushort Bs_lo[128][40];

    const int t    = threadIdx.x;
    const int bn0  = blockIdx.x * 128;
    const int bm0  = blockIdx.y * 128;
    const int kz0  = blockIdx.z * Kper;
    const int wid  = t >> 6;
    const int lane = t & 63;
    const int wm   = (wid >> 1) * 64;     // wave's m-offset in tile
    const int wn   = (wid & 1) * 64;      // wave's n-offset in tile
    const int lr   = lane & 15;           // frag row/col
    const int lk   = lane >> 4;           // frag k-group (k0 = lk*8)

    f32x4 acc[4][4];
    #pragma unroll
    for (int i = 0; i < 4; ++i)
        #pragma unroll
        for (int j = 0; j < 4; ++j) {
            f32x4 z = {0.f, 0.f, 0.f, 0.f};
            acc[i][j] = z;
        }

    for (int kk = 0; kk < Kper; kk += 32) {
        const int k0 = kz0 + kk;

        // ---- stage A: 128 rows x 32 k fp32 -> hi/lo planes (coalesced) ----
        #pragma unroll
        for (int i = 0; i < 4; ++i) {
            int c   = t + i * 256;
            int row = c >> 3;             // 8 float4-chunks per row
            int k4  = (c & 7) * 4;
            float4 v = *(const float4*)(A + (size_t)(bm0 + row) * K + k0 + k4);
            ushort4 hi, lo;
            split_bf(v.x, hi.x, lo.x);
            split_bf(v.y, hi.y, lo.y);
            split_bf(v.z, hi.z, lo.z);
            split_bf(v.w, hi.w, lo.w);
            *(ushort4*)&As_hi[row][k4] = hi;
            *(ushort4*)&As_lo[row][k4] = lo;
        }
        // ---- stage B: 32 k x 128 n fp32 -> hi/lo planes, transposed ----
        #pragma unroll
        for (int i = 0; i < 4; ++i) {
            int c   = t + i * 256;
            int kr  = c >> 5;             // 32 float4-chunks per k-row
            int n4  = (c & 31) * 4;
            int n   = bn0 + n4;
            float4 v = make_float4(0.f, 0.f, 0.f, 0.f);
            if (n + 4 <= N)
                v = *(const float4*)(W + (size_t)(k0 + kr) * N + n);
            ushort hi, lo;
            split_bf(v.x, hi, lo); Bs_hi[n4 + 0][kr] = hi; Bs_lo[n4 + 0][kr] = lo;
            split_bf(v.y, hi, lo); Bs_hi[n4 + 1][kr] = hi; Bs_lo[n4 + 1][kr] = lo;
            split_bf(v.z, hi, lo); Bs_hi[n4 + 2][kr] = hi; Bs_lo[n4 + 2][kr] = lo;
            split_bf(v.w, hi, lo); Bs_hi[n4 + 3][kr] = hi; Bs_lo[n4 + 3][kr] = lo;
        }
        __syncthreads();

        // ---- fragments ----
        short8 ah[4], al[4], bh[4], bl[4];
        #pragma unroll
        for (int mi = 0; mi < 4; ++mi) {
            ah[mi] = *(const short8*)&As_hi[wm + mi * 16 + lr][lk * 8];
            al[mi] = *(const short8*)&As_lo[wm + mi * 16 + lr][lk * 8];
        }
        #pragma unroll
        for (int ni = 0; ni < 4; ++ni) {
            bh[ni] = *(const short8*)&Bs_hi[wn + ni * 16 + lr][lk * 8];
            bl[ni] = *(const short8*)&Bs_lo[wn + ni * 16 + lr][lk * 8];
        }

        // ---- 3-pass MFMA ----
        #pragma unroll
        for (int mi = 0; mi < 4; ++mi)
            #pragma unroll
            for (int ni = 0; ni < 4; ++ni) {
                f32x4 c0 = acc[mi][ni];
                c0 = __builtin_amdgcn_mfma_f32_16x16x32_bf16(ah[mi], bh[ni], c0, 0, 0, 0);
                c0 = __builtin_amdgcn_mfma_f32_16x16x32_bf16(ah[mi], bl[ni], c0, 0, 0, 0);
                c0 = __builtin_amdgcn_mfma_f32_16x16x32_bf16(al[mi], bh[ni], c0, 0, 0, 0);
                acc[mi][ni] = c0;
            }
        __syncthreads();
    }

    // ---- epilogue: atomic accumulate (split-K), bias on split 0 ----
    const bool addb = (bias != nullptr) && (blockIdx.z == 0);
    #pragma unroll
    for (int ni = 0; ni < 4; ++ni) {
        int n = bn0 + wn + ni * 16 + lr;
        if (n >= N) continue;
        float bv = addb ? bias[n] : 0.f;
        #pragma unroll
        for (int mi = 0; mi < 4; ++mi) {
            int mbase = bm0 + wm + mi * 16 + lk * 4;
            #pragma unroll
            for (int r = 0; r < 4; ++r) {
                float v = acc[mi][ni][r] + bv;
                atomicAdd(&C[(size_t)(mbase + r) * N + n], v);
            }
        }
    }
}

// ---------------------------------------------------------------------------
// RMSNorm over 1024 cols (+ optional SiLU). One block (256 thr) per row.
// ---------------------------------------------------------------------------
template <bool SILU>
__global__ __launch_bounds__(256) void rmsnorm_kernel(
    const float* __restrict__ X, const float* __restrict__ g,
    float* __restrict__ Y)
{
    const int row = blockIdx.x;
    const float* x = X + (size_t)row * 1024;
    float4 v = *(const float4*)(x + threadIdx.x * 4);
    float ss = v.x * v.x + v.y * v.y + v.z * v.z + v.w * v.w;
    #pragma unroll
    for (int off = 32; off > 0; off >>= 1) ss += __shfl_down(ss, off);

    __shared__ float wsum[4];
    const int wid = threadIdx.x >> 6;
    if ((threadIdx.x & 63) == 0) wsum[wid] = ss;
    __syncthreads();
    const float tot = wsum[0] + wsum[1] + wsum[2] + wsum[3];
    const float rs = 1.0f / sqrtf(tot * (1.0f / 1024.0f) + 1e-5f);

    float4 gv = *(const float4*)(g + threadIdx.x * 4);
    float4 o;
    o.x = v.x * rs * gv.x;
    o.y = v.y * rs * gv.y;
    o.z = v.z * rs * gv.z;
    o.w = v.w * rs * gv.w;
    if (SILU) {
        o.x = silu_precise(o.x);
        o.y = silu_precise(o.y);
        o.z = silu_precise(o.z);
        o.w = silu_precise(o.w);
    }
    *(float4*)(Y + (size_t)row * 1024 + threadIdx.x * 4) = o;
}

// ---------------------------------------------------------------------------
// Conv state shift + depthwise conv + SiLU. One thread per (b, c).
// ---------------------------------------------------------------------------
__global__ __launch_bounds__(256) void conv_kernel(
    const float* __restrict__ conv_state, const float* __restrict__ zx,
    const float* __restrict__ conv_w, const float* __restrict__ conv_b,
    float* __restrict__ conv_state_out, float* __restrict__ xbc_out)
{
    const int gid = blockIdx.x * 256 + threadIdx.x;  // b*CONV_DIM + c
    const int b = gid / CONV_DIM;
    const int c = gid - b * CONV_DIM;

    float4 cs = *(const float4*)(conv_state + (size_t)gid * 4);
    float xn = zx[(size_t)b * D_IN_PROJ + D_INNER + c];
    float4 w = *(const float4*)(conv_w + c * 4);

    float s = cs.y * w.x + cs.z * w.y + cs.w * w.z + xn * w.w + conv_b[c];
    float r = silu_precise(s);

    float4 o = make_float4(cs.y, cs.z, cs.w, xn);
    *(float4*)(conv_state_out + (size_t)gid * 4) = o;
    xbc_out[gid] = r;
}

// ---------------------------------------------------------------------------
// SSM state update + y.  Block = (head h, batch b), 256 threads.
// Coalesced mapping: n0 = (t&31)*4, p = (t>>5) + 8*i; wave touches contiguous
// 1024-B segments per VMEM op. 32-lane shfl_xor y-reduction.
// ---------------------------------------------------------------------------
__global__ __launch_bounds__(256) void ssm_kernel(
    const float* __restrict__ ssm_state, const float* __restrict__ xbc,
    const float* __restrict__ zx, const float* __restrict__ A_log,
    const float* __restrict__ dt_bias, const float* __restrict__ Dp,
    float* __restrict__ ssm_out, float* __restrict__ yz)
{
    const int h = blockIdx.x;   // 0..31
    const int b = blockIdx.y;   // 0..511
    const int t = threadIdx.x;  // 0..255
    const int lane_n = t & 31;
    const int n0 = lane_n * 4;
    const int pg = t >> 5;

    float dtv = zx[(size_t)b * D_IN_PROJ + (D_INNER + CONV_DIM) + h] + dt_bias[h];
    dtv = (dtv > 20.f) ? dtv : log1pf(expf(dtv));
    const float a  = -expf(A_log[h]);
    const float da = expf(dtv * a);
    const float dcoef = Dp[h];

    const float* xrow = xbc + (size_t)b * CONV_DIM;

    const float4 bb = *(const float4*)(xrow + D_INNER + n0);
    const float4 cc = *(const float4*)(xrow + D_INNER + D_STATE + n0);

    const size_t slab = ((size_t)b * NHEADS + h) * (HEADDIM * D_STATE);
    const float* sp = ssm_state + slab;
    float*       so = ssm_out   + slab;

    #pragma unroll
    for (int i = 0; i < 8; ++i) {
        const int p = pg + i * 8;
        const float xh = xrow[h * HEADDIM + p];
        const float coef = dtv * xh;

        const size_t off = (size_t)p * D_STATE + n0;
        float4 s = *(const float4*)(sp + off);
        float4 ns;
        ns.x = s.x * da + coef * bb.x;
        ns.y = s.y * da + coef * bb.y;
        ns.z = s.z * da + coef * bb.z;
        ns.w = s.w * da + coef * bb.w;
        *(float4*)(so + off) = ns;

        float y = ns.x * cc.x + ns.y * cc.y + ns.z * cc.z + ns.w * cc.w;
        y += __shfl_xor(y, 16);
        y += __shfl_xor(y, 8);
        y += __shfl_xor(y, 4);
        y += __shfl_xor(y, 2);
        y += __shfl_xor(y, 1);

        if (lane_n == 0) {
            float z = zx[(size_t)b * D_IN_PROJ + h * HEADDIM + p];
            float yv = y + dcoef * xh;
            yz[(size_t)b * D_INNER + h * HEADDIM + p] = yv * silu_precise(z);
        }
    }
}

// ---------------------------------------------------------------------------

extern "C" void kernel_launch(void* const* d_in, const int* in_sizes, int n_in,
                              void* d_out, int out_size, void* d_ws, size_t ws_size,
                              hipStream_t stream)
{
    const float* x          = (const float*)d_in[0];   // 512 x 1536
    const float* conv_state = (const float*)d_in[1];   // 512 x 2304 x 4
    const float* ssm_state  = (const float*)d_in[2];   // 512 x 32 x 64 x 128
    const float* w_in       = (const float*)d_in[3];   // 1536 x 1024
    const float* b_in       = (const float*)d_in[4];   // 1024
    const float* g_in       = (const float*)d_in[5];   // 1024
    const float* W_inproj   = (const float*)d_in[6];   // 1024 x 4384
    const float* conv_w     = (const float*)d_in[7];   // 2304 x 4
    const float* conv_b     = (const float*)d_in[8];   // 2304
    const float* A_log      = (const float*)d_in[9];   // 32
    const float* dt_bias    = (const float*)d_in[10];  // 32
    const float* Dp         = (const float*)d_in[11];  // 32
    const float* W_mamba_out= (const float*)d_in[12];  // 2048 x 1024
    const float* w_out      = (const float*)d_in[13];  // 1024 x 1024
    const float* b_out      = (const float*)d_in[14];  // 1024
    const float* g_outnorm  = (const float*)d_in[15];  // 1024

    float* out_y    = (float*)d_out;                                   // 512*1024
    float* out_conv = out_y + (size_t)B_SZ * OUT_DIM;                  // 512*2304*4
    float* out_ssm  = out_conv + (size_t)B_SZ * CONV_DIM * 4;          // 512*32*64*128

    // GEMM outputs FIRST and contiguous, so one zero-fill covers all four.
    float* ws  = (float*)d_ws;
    float* t1  = ws;                                  // 512*1024 (gemm1 out)
    float* zx  = t1  + (size_t)B_SZ * MAMBA_DIM;      // 512*4384 (gemm2 out)
    float* u   = zx  + (size_t)B_SZ * D_IN_PROJ;      // 512*1024 (gemm3 out)
    float* t2  = u   + (size_t)B_SZ * MAMBA_DIM;      // 512*1024 (gemm4 out)
    float* h   = t2  + (size_t)B_SZ * MAMBA_DIM;      // 512*1024
    float* xbc = h   + (size_t)B_SZ * MAMBA_DIM;      // 512*2304
    float* yzb = xbc + (size_t)B_SZ * CONV_DIM;       // 512*2048

    const int gemm_out_floats = B_SZ * (MAMBA_DIM + D_IN_PROJ + MAMBA_DIM + MAMBA_DIM);

    // 0) zero the split-K accumulation buffers (t1, zx, u, t2 contiguous)
    zero_kernel<<<2048, 256, 0, stream>>>((float4*)ws, gemm_out_floats / 4);

    // 1) t1 += x @ w_in + b_in      (tiles 8x4, split 8, Kper=192 -> 256 blk)
    gemm_bf16x3_splitk<<<dim3(MAMBA_DIM / 128, B_SZ / 128, 8), 256, 0, stream>>>(
        x, w_in, b_in, t1, B_SZ, MAMBA_DIM, INPUT_DIM, INPUT_DIM / 8);
    // 2) h = silu(rmsnorm(t1, g_in))
    rmsnorm_kernel<true><<<B_SZ, 256, 0, stream>>>(t1, g_in, h);
    // 3) zx += h @ W_inproj         (tiles 35x4, split 4, Kper=256 -> 560 blk)
    gemm_bf16x3_splitk<<<dim3((D_IN_PROJ + 127) / 128, B_SZ / 128, 4), 256, 0, stream>>>(
        h, W_inproj, nullptr, zx, B_SZ, D_IN_PROJ, MAMBA_DIM, MAMBA_DIM / 4);
    // 4) conv state shift + conv + silu
    conv_kernel<<<(B_SZ * CONV_DIM) / 256, 256, 0, stream>>>(
        conv_state, zx, conv_w, conv_b, out_conv, xbc);
    // 5) ssm update + gated y
    ssm_kernel<<<dim3(NHEADS, B_SZ), 256, 0, stream>>>(
        ssm_state, xbc, zx, A_log, dt_bias, Dp, out_ssm, yzb);
    // 6) u += yz @ W_mamba_out      (tiles 8x4, split 8, Kper=256 -> 256 blk)
    gemm_bf16x3_splitk<<<dim3(MAMBA_DIM / 128, B_SZ / 128, 8), 256, 0, stream>>>(
        yzb, W_mamba_out, nullptr, u, B_SZ, MAMBA_DIM, D_INNER, D_INNER / 8);
    // 7) t2 += u @ w_out + b_out    (tiles 8x4, split 8, Kper=128 -> 256 blk)
    gemm_bf16x3_splitk<<<dim3(OUT_DIM / 128, B_SZ / 128, 8), 256, 0, stream>>>(
        u, w_out, b_out, t2, B_SZ, OUT_DIM, MAMBA_DIM, MAMBA_DIM / 8);
    // 8) out_y = rmsnorm(t2, g_outnorm)
    rmsnorm_kernel<false><<<B_SZ, 256, 0, stream>>>(t2, g_outnorm, out_y);
}